// Round 1
// 1041.249 us; speedup vs baseline: 1.1880x; 1.1880x over previous
//
#include <hip/hip_runtime.h>
#include <hip/hip_bf16.h>
#include <cstdint>

typedef __bf16 bf16x8 __attribute__((ext_vector_type(8)));
typedef float floatx4 __attribute__((ext_vector_type(4)));

__device__ __forceinline__ unsigned short f2bf(float f) {
  union { float f; unsigned int u; } v;
  v.f = f;
  unsigned int r = v.u + 0x7FFFu + ((v.u >> 16) & 1u);  // RNE
  return (unsigned short)(r >> 16);
}

// ---------------------------------------------------------------------------
// Kernel 1: gumbel 2:4 mask + masked weight -> bf16  (grid-stride)
// ---------------------------------------------------------------------------
__global__ __launch_bounds__(256) void mask_weight_k(
    const float4* __restrict__ w, const float4* __restrict__ s,
    const float4* __restrict__ u, ushort4* __restrict__ wb, int ngroups)
{
  const int stride = gridDim.x * blockDim.x;
  for (int gid = blockIdx.x * blockDim.x + threadIdx.x; gid < ngroups; gid += stride) {
    float4 sv = s[gid];
    float4 uv = u[gid];
    float4 wv = w[gid];
    const float EPS = 1e-10f;
    float y[4];
    y[0] = sv.x - logf(-logf(uv.x + EPS) + EPS);
    y[1] = sv.y - logf(-logf(uv.y + EPS) + EPS);
    y[2] = sv.z - logf(-logf(uv.z + EPS) + EPS);
    y[3] = sv.w - logf(-logf(uv.w + EPS) + EPS);
    int i1 = 0;
#pragma unroll
    for (int k = 1; k < 4; ++k)
      if (y[k] > y[i1]) i1 = k;
    int i2 = -1;
#pragma unroll
    for (int k = 0; k < 4; ++k) {
      if (k == i1) continue;
      if (i2 < 0 || y[k] > y[i2]) i2 = k;
    }
    ushort4 o;
    o.x = (i1 == 0 || i2 == 0) ? f2bf(wv.x) : (unsigned short)0;
    o.y = (i1 == 1 || i2 == 1) ? f2bf(wv.y) : (unsigned short)0;
    o.z = (i1 == 2 || i2 == 2) ? f2bf(wv.z) : (unsigned short)0;
    o.w = (i1 == 3 || i2 == 3) ? f2bf(wv.w) : (unsigned short)0;
    wb[gid] = o;
  }
}

// ---------------------------------------------------------------------------
// Kernel 2: x fp32 -> bf16  (grid-stride)
// ---------------------------------------------------------------------------
__global__ __launch_bounds__(256) void cast_x_k(
    const float4* __restrict__ x, ushort4* __restrict__ xb, int n4)
{
  const int stride = gridDim.x * blockDim.x;
  for (int i = blockIdx.x * blockDim.x + threadIdx.x; i < n4; i += stride) {
    float4 v = x[i];
    ushort4 o;
    o.x = f2bf(v.x);
    o.y = f2bf(v.y);
    o.z = f2bf(v.z);
    o.w = f2bf(v.w);
    xb[i] = o;
  }
}

// ---------------------------------------------------------------------------
// Kernel 3: bf16 NT GEMM, 256x256 tile, BK=64, 8 waves, 8-phase schedule.
//
// Geometry: 512 thr = 8 waves (2M x 4N); per-wave C = 128x64; acc[8][4].
// LDS 128 KiB: A [2buf][256][128B] @0, B @65536. Tile halves: h0 rows 0..127,
// h1 rows 128..255. Per-wave reads: A-half = wr (fixed); phase quadrant
// (MQ,NQ): A rows MQ*128+wr*64+.., B rows NQ*128+wc*32+..  =>
//   A0(t) dead after ph2, B0(t) after ph3, A1/B1 after ph4.
// Stage slots (1 half-tile = 2 global_load_lds/thread per phase):
//   ph1: A1(t+1)->obuf  ph2: B1(t+1)->obuf  ph3: A0(t+2)->cur  ph4: B0(t+2)->cur
// Each slot is >=1 barrier after the last read of its target (race-free).
// vmcnt(4) once per tile at ph4 (keeps A0/B0(t+2) in flight -- never 0 in
// main loop).  Bank swizzle: LDS slot (r,c16B) holds global chunk c^(r&7);
// linear LDS dest (global_load_lds), pre-swizzled global source; readers
// use c' = (ks*4+qm)^(rm&7).  ds_read_b128 spread = 8 lanes/bank-group.
// ---------------------------------------------------------------------------
__global__ __launch_bounds__(512, 2) void gemm_bt(
    const __bf16* __restrict__ A, const __bf16* __restrict__ B,
    const float* __restrict__ bias, float* __restrict__ C,
    int M, int N, int K)
{
  __shared__ char lds[131072];

  const int tid  = threadIdx.x;
  const int lane = tid & 63;
  const int wave = tid >> 6;
  const int wr = wave >> 2;     // 0..1
  const int wc = wave & 3;      // 0..3
  const int rm = lane & 15;
  const int qm = lane >> 4;
  const int x7 = rm & 7;

  const int bm = blockIdx.y * 256;
  const int bn = blockIdx.x * 256;

  // staging coords: LDS half-tile byte o = tid*16 (+8192); row r = o>>7
  const int so0 = tid * 16;
  const int sr0 = tid >> 3;                       // 0..63 (and +64)
  const int scb = ((tid & 7) ^ (sr0 & 7)) * 16;   // pre-swizzled global chunk
  const size_t ldb = (size_t)K * 2;

  const char* gA = (const char*)(A + (size_t)bm * K);
  const char* gB = (const char*)(B + (size_t)bn * K);
  char* const ldsA = (char*)lds;
  char* const ldsB = (char*)lds + 65536;

  // reader lane byte offsets (ks=0); ks=1 flips chunk bit 4*16 -> ^64
  const int laneA0 = (wr * 64 + rm) * 128 + ((qm ^ x7) * 16);
  const int laneA1 = laneA0 ^ 64;
  const int laneB0 = (wc * 32 + rm) * 128 + ((qm ^ x7) * 16);
  const int laneB1 = laneB0 ^ 64;

  floatx4 acc[8][4];
#pragma unroll
  for (int i = 0; i < 8; ++i)
#pragma unroll
    for (int j = 0; j < 4; ++j)
      acc[i][j] = (floatx4){0.f, 0.f, 0.f, 0.f};

#define STAGE(ldsHalf, gHalf)                                                          \
  do {                                                                                 \
    __builtin_amdgcn_global_load_lds(                                                  \
        (const __attribute__((address_space(1))) void*)((gHalf) + (size_t)sr0 * ldb + scb),        \
        (__attribute__((address_space(3))) void*)((ldsHalf) + so0), 16, 0, 0);                      \
    __builtin_amdgcn_global_load_lds(                                                  \
        (const __attribute__((address_space(1))) void*)((gHalf) + (size_t)(sr0 + 64) * ldb + scb), \
        (__attribute__((address_space(3))) void*)((ldsHalf) + so0 + 8192), 16, 0, 0);               \
  } while (0)

#define MFMA_BF16 __builtin_amdgcn_mfma_f32_16x16x32_bf16

#define PHASE(MQ, NQ, STAGE_STMT, TAIL_STMT)                                           \
  {                                                                                    \
    const char* pA  = bufA + (MQ) * 16384 + laneA0;                                    \
    const char* pAx = bufA + (MQ) * 16384 + laneA1;                                    \
    const char* pB  = bufB + (NQ) * 16384 + laneB0;                                    \
    const char* pBx = bufB + (NQ) * 16384 + laneB1;                                    \
    bf16x8 A00 = *(const bf16x8*)(pA);                                                 \
    bf16x8 A10 = *(const bf16x8*)(pA + 2048);                                          \
    bf16x8 A20 = *(const bf16x8*)(pA + 4096);                                          \
    bf16x8 A30 = *(const bf16x8*)(pA + 6144);                                          \
    bf16x8 B00 = *(const bf16x8*)(pB);                                                 \
    bf16x8 B10 = *(const bf16x8*)(pB + 2048);                                          \
    bf16x8 A01 = *(const bf16x8*)(pAx);                                                \
    bf16x8 A11 = *(const bf16x8*)(pAx + 2048);                                         \
    bf16x8 A21 = *(const bf16x8*)(pAx + 4096);                                         \
    bf16x8 A31 = *(const bf16x8*)(pAx + 6144);                                         \
    bf16x8 B01 = *(const bf16x8*)(pBx);                                                \
    bf16x8 B11 = *(const bf16x8*)(pBx + 2048);                                         \
    STAGE_STMT;                                                                        \
    __builtin_amdgcn_s_barrier();                                                      \
    __builtin_amdgcn_s_setprio(1);                                                     \
    acc[(MQ)*4+0][(NQ)*2+0] = MFMA_BF16(A00, B00, acc[(MQ)*4+0][(NQ)*2+0], 0, 0, 0);   \
    acc[(MQ)*4+0][(NQ)*2+1] = MFMA_BF16(A00, B10, acc[(MQ)*4+0][(NQ)*2+1], 0, 0, 0);   \
    acc[(MQ)*4+1][(NQ)*2+0] = MFMA_BF16(A10, B00, acc[(MQ)*4+1][(NQ)*2+0], 0, 0, 0);   \
    acc[(MQ)*4+1][(NQ)*2+1] = MFMA_BF16(A10, B10, acc[(MQ)*4+1][(NQ)*2+1], 0, 0, 0);   \
    acc[(MQ)*4+2][(NQ)*2+0] = MFMA_BF16(A20, B00, acc[(MQ)*4+2][(NQ)*2+0], 0, 0, 0);   \
    acc[(MQ)*4+2][(NQ)*2+1] = MFMA_BF16(A20, B10, acc[(MQ)*4+2][(NQ)*2+1], 0, 0, 0);   \
    acc[(MQ)*4+3][(NQ)*2+0] = MFMA_BF16(A30, B00, acc[(MQ)*4+3][(NQ)*2+0], 0, 0, 0);   \
    acc[(MQ)*4+3][(NQ)*2+1] = MFMA_BF16(A30, B10, acc[(MQ)*4+3][(NQ)*2+1], 0, 0, 0);   \
    acc[(MQ)*4+0][(NQ)*2+0] = MFMA_BF16(A01, B01, acc[(MQ)*4+0][(NQ)*2+0], 0, 0, 0);   \
    acc[(MQ)*4+0][(NQ)*2+1] = MFMA_BF16(A01, B11, acc[(MQ)*4+0][(NQ)*2+1], 0, 0, 0);   \
    acc[(MQ)*4+1][(NQ)*2+0] = MFMA_BF16(A11, B01, acc[(MQ)*4+1][(NQ)*2+0], 0, 0, 0);   \
    acc[(MQ)*4+1][(NQ)*2+1] = MFMA_BF16(A11, B11, acc[(MQ)*4+1][(NQ)*2+1], 0, 0, 0);   \
    acc[(MQ)*4+2][(NQ)*2+0] = MFMA_BF16(A21, B01, acc[(MQ)*4+2][(NQ)*2+0], 0, 0, 0);   \
    acc[(MQ)*4+2][(NQ)*2+1] = MFMA_BF16(A21, B11, acc[(MQ)*4+2][(NQ)*2+1], 0, 0, 0);   \
    acc[(MQ)*4+3][(NQ)*2+0] = MFMA_BF16(A31, B01, acc[(MQ)*4+3][(NQ)*2+0], 0, 0, 0);   \
    acc[(MQ)*4+3][(NQ)*2+1] = MFMA_BF16(A31, B11, acc[(MQ)*4+3][(NQ)*2+1], 0, 0, 0);   \
    __builtin_amdgcn_s_setprio(0);                                                     \
    TAIL_STMT;                                                                         \
    __builtin_amdgcn_s_barrier();                                                      \
  }

  const int NT = K >> 6;  // K/64 tiles; requires NT >= 3

  // Prologue: stage A0(0),B0(0),A1(0),B1(0),A0(1),B0(1); allow A0/B0(1) in flight.
  STAGE(ldsA, gA);
  STAGE(ldsB, gB);
  STAGE(ldsA + 16384, gA + (size_t)128 * ldb);
  STAGE(ldsB + 16384, gB + (size_t)128 * ldb);
  STAGE(ldsA + 32768, gA + 128);
  STAGE(ldsB + 32768, gB + 128);
  asm volatile("s_waitcnt vmcnt(4)" ::: "memory");
  __builtin_amdgcn_s_barrier();

  int t = 0;
  for (; t < NT - 2; ++t) {
    const int cur = t & 1;
    char* bufA  = ldsA + cur * 32768;
    char* bufB  = ldsB + cur * 32768;
    char* obufA = ldsA + (cur ^ 1) * 32768;
    char* obufB = ldsB + (cur ^ 1) * 32768;
    const char* gAt1 = gA + (size_t)(t + 1) * 128;
    const char* gBt1 = gB + (size_t)(t + 1) * 128;
    const char* gAt2 = gA + (size_t)(t + 2) * 128;
    const char* gBt2 = gB + (size_t)(t + 2) * 128;

    PHASE(0, 0, STAGE(obufA + 16384, gAt1 + (size_t)128 * ldb), ((void)0));
    PHASE(0, 1, STAGE(obufB + 16384, gBt1 + (size_t)128 * ldb), ((void)0));
    PHASE(1, 0, STAGE(bufA, gAt2), ((void)0));
    PHASE(1, 1, STAGE(bufB, gBt2),
          asm volatile("s_waitcnt vmcnt(4)" ::: "memory"));
  }

  // t == NT-2: stage only A1/B1(NT-1); full drain before the last tile.
  {
    const int cur = t & 1;
    char* bufA  = ldsA + cur * 32768;
    char* bufB  = ldsB + cur * 32768;
    char* obufA = ldsA + (cur ^ 1) * 32768;
    char* obufB = ldsB + (cur ^ 1) * 32768;
    const char* gAt1 = gA + (size_t)(t + 1) * 128;
    const char* gBt1 = gB + (size_t)(t + 1) * 128;

    PHASE(0, 0, STAGE(obufA + 16384, gAt1 + (size_t)128 * ldb), ((void)0));
    PHASE(0, 1, STAGE(obufB + 16384, gBt1 + (size_t)128 * ldb), ((void)0));
    PHASE(1, 0, ((void)0), ((void)0));
    PHASE(1, 1, ((void)0),
          asm volatile("s_waitcnt vmcnt(0)" ::: "memory"));
  }

  // t == NT-1: compute only.
  {
    const int cur = (NT - 1) & 1;
    char* bufA = ldsA + cur * 32768;
    char* bufB = ldsB + cur * 32768;
    PHASE(0, 0, ((void)0), ((void)0));
    PHASE(0, 1, ((void)0), ((void)0));
    PHASE(1, 0, ((void)0), ((void)0));
    PHASE(1, 1, ((void)0), ((void)0));
  }

#undef PHASE
#undef MFMA_BF16
#undef STAGE

  // Epilogue: C/D layout row = qm*4 + r, col = rm.
#pragma unroll
  for (int nj = 0; nj < 4; ++nj) {
    const int n = bn + (nj >> 1) * 128 + wc * 32 + (nj & 1) * 16 + rm;
    const float bv = bias[n];
#pragma unroll
    for (int mi = 0; mi < 8; ++mi) {
      const int m = bm + (mi >> 2) * 128 + wr * 64 + (mi & 3) * 16 + qm * 4;
      float* cp = C + (size_t)m * N + n;
#pragma unroll
      for (int r = 0; r < 4; ++r)
        cp[(size_t)r * N] = acc[mi][nj][r] + bv;
    }
  }
}

// ---------------------------------------------------------------------------
extern "C" void kernel_launch(void* const* d_in, const int* in_sizes, int n_in,
                              void* d_out, int out_size, void* d_ws, size_t ws_size,
                              hipStream_t stream)
{
  const float* x      = (const float*)d_in[0];
  const float* weight = (const float*)d_in[1];
  const float* bias   = (const float*)d_in[2];
  const float* scores = (const float*)d_in[3];
  const float* noise  = (const float*)d_in[4];
  float* out = (float*)d_out;

  const int N = in_sizes[2];            // 4096 (D_OUT)
  const int K = in_sizes[1] / N;        // 4096 (D_IN)
  const int M = in_sizes[0] / K;        // 16384 (B*S)

  __bf16* xb = (__bf16*)d_ws;
  __bf16* wb = (__bf16*)((char*)d_ws + (size_t)M * K * sizeof(__bf16));

  const int ngroups = (N * K) / 4;      // 4,194,304
  mask_weight_k<<<dim3(2048), dim3(256), 0, stream>>>(
      (const float4*)weight, (const float4*)scores, (const float4*)noise,
      (ushort4*)wb, ngroups);

  const int n4 = (int)(((size_t)M * K) / 4);  // 16,777,216
  cast_x_k<<<dim3(2048), dim3(256), 0, stream>>>(
      (const float4*)x, (ushort4*)xb, n4);

  dim3 grid(N / 256, M / 256);
  gemm_bt<<<grid, dim3(512), 0, stream>>>(xb, wb, bias, out, M, N, K);
}